// Round 2
// baseline (892.510 us; speedup 1.0000x reference)
//
#include <hip/hip_runtime.h>

// GRU: B=256, T=2048, I=10, H=64, fp32 in/out.
// Round-5 theory: with B=256 batches on 256 CUs and a strictly serial t-loop,
// only per-step CRITICAL-PATH latency matters (utilization is irrelevant).
// Round-4's 2-wave K-split paid __syncthreads (= s_waitcnt vmcnt(0)! -> the
// output store becomes a blocking L2-ack wait every step) + ds_bpermute shfl
// + barrier jitter ~ 300+ cyc to save 96 cyc of dot2 issue. Net loser.
// Fix: single wave per batch. No barrier, no shuffle, stores truly
// fire-and-forget (vmcnt never waited). Keep round-4's proven pieces:
// asm-pinned f16 weights + waves_per_eu(1,1) (kills the round-3 spill),
// x staged to LDS f16 (zero vmem loads in the loop), exp2/rcp gates with
// log2e prescaled into weights, x reads software-pipelined one step ahead.
// h broadcast via LDS f16; same-wave in-order DS pipe -> write-then-read
// ordering is free (round-3-verified pattern).

#define Bn 256
#define Tn 2048
#define In 10
#define Hn 64

typedef _Float16 h2 __attribute__((ext_vector_type(2)));

__device__ __forceinline__ float dot2(h2 a, h2 b, float c) {
    return __builtin_amdgcn_fdot2(a, b, c, false);
}

extern "C" __global__
__attribute__((amdgpu_flat_work_group_size(64, 64), amdgpu_waves_per_eu(1, 1)))
void gru_kernel(
    const float* __restrict__ noise,  // (B, T, I)
    const float* __restrict__ w_ih,   // (3H, I)
    const float* __restrict__ w_hh,   // (3H, H)
    const float* __restrict__ b_ih,   // (3H)
    const float* __restrict__ b_hh,   // (3H)
    float* __restrict__ out)          // (B, T, H)
{
    const int b = blockIdx.x;
    const int j = threadIdx.x;  // hidden unit 0..63

    __shared__ alignas(16) unsigned short xbuf[Tn * 12];  // x f16, stride 12 shorts (24 B)
    __shared__ alignas(16) unsigned short hbuf[Hn];       // h f16, single buffer

    // ---- stage x (f32 -> f16) into LDS: 32 chunks of 64 rows ----
    {
        const float* xp = noise + (size_t)b * Tn * In;
        for (int c = 0; c < Tn / 64; ++c) {
            const int t = c * 64 + j;
            const float* px = xp + (size_t)t * In;
            float v[In];
#pragma unroll
            for (int i = 0; i < In; i += 2) {
                float2 f = *(const float2*)(px + i);  // 8B-aligned: t*40+i*4
                v[i] = f.x; v[i + 1] = f.y;
            }
            unsigned int p[5];
#pragma unroll
            for (int i = 0; i < 5; ++i)
                p[i] = __builtin_bit_cast(unsigned int,
                           h2{(_Float16)v[2 * i], (_Float16)v[2 * i + 1]});
            unsigned int* xw = (unsigned int*)(xbuf + t * 12);
            *(uint2*)(xw + 0) = uint2{p[0], p[1]};
            *(uint2*)(xw + 2) = uint2{p[2], p[3]};
            xw[4] = p[4];
        }
        hbuf[j] = 0;  // f16 +0.0
    }

    // ---- per-lane weights, prescaled for exp2-native gates ----
    const float SR = -1.44269504f;   // -log2(e): sigmoid(u) = rcp(1+exp2(SR*u))
    const float SN =  2.88539008f;   // 2*log2(e): tanh(p) = 1-2*rcp(exp2(SN*p)+1)

    h2 wr[32], wz[32], wn[32];       // this lane's 3 full W_hh rows, f16 (96 VGPRs)
    {
        const float* pr = w_hh + (size_t)(0 * Hn + j) * Hn;
        const float* pz = w_hh + (size_t)(1 * Hn + j) * Hn;
        const float* pn = w_hh + (size_t)(2 * Hn + j) * Hn;
#pragma unroll
        for (int k = 0; k < 32; ++k) {
            wr[k] = h2{(_Float16)(SR * pr[2 * k]), (_Float16)(SR * pr[2 * k + 1])};
            wz[k] = h2{(_Float16)(SR * pz[2 * k]), (_Float16)(SR * pz[2 * k + 1])};
            wn[k] = h2{(_Float16)(SN * pn[2 * k]), (_Float16)(SN * pn[2 * k + 1])};
        }
    }
    float wir[In], wiz[In], win[In];  // input-proj rows stay fp32 (30 VGPRs)
#pragma unroll
    for (int i = 0; i < In; ++i) {
        wir[i] = SR * w_ih[(0 * Hn + j) * In + i];
        wiz[i] = SR * w_ih[(1 * Hn + j) * In + i];
        win[i] = SN * w_ih[(2 * Hn + j) * In + i];
    }
    const float brz_r = SR * (b_ih[0 * Hn + j] + b_hh[0 * Hn + j]);
    const float brz_z = SR * (b_ih[1 * Hn + j] + b_hh[1 * Hn + j]);
    const float bi_n  = SN * b_ih[2 * Hn + j];
    const float bh_n  = SN * b_hh[2 * Hn + j];

    // Pin weights into VGPRs: opaque to remat, allocator must keep them live.
#pragma unroll
    for (int k = 0; k < 32; ++k)
        asm volatile("" : "+v"(wr[k]), "+v"(wz[k]), "+v"(wn[k]));
#pragma unroll
    for (int i = 0; i < In; ++i)
        asm volatile("" : "+v"(wir[i]), "+v"(wiz[i]), "+v"(win[i]));

    float hold = 0.0f;
    float* __restrict__ op = out + (size_t)b * Tn * Hn;

    // Preload x(0) packed (pipelined one step ahead thereafter).
    unsigned int xc0, xc1, xc2, xc3, xc4;
    {
        const unsigned int* xr = (const unsigned int*)xbuf;
        uint2 a = *(const uint2*)(xr + 0);
        uint2 c = *(const uint2*)(xr + 2);
        xc0 = a.x; xc1 = a.y; xc2 = c.x; xc3 = c.y; xc4 = xr[4];
    }

    for (int t = 0; t < Tn; ++t) {
        // h broadcast: 8x ds_read_b128 from uniform addr (pure broadcast).
        // Same wave wrote hbuf last iteration -> in-order DS pipe, no barrier.
        const uint4* hq4 = (const uint4*)hbuf;
        uint4 q0 = hq4[0], q1 = hq4[1], q2 = hq4[2], q3 = hq4[3];
        uint4 q4 = hq4[4], q5 = hq4[5], q6 = hq4[6], q7 = hq4[7];

        // Prefetch x(t+1): issued now, consumed next iteration (latency hidden).
        unsigned int xn0, xn1, xn2, xn3, xn4;
        {
            const int tn = (t + 1 < Tn) ? (t + 1) : t;
            const unsigned int* xr = (const unsigned int*)(xbuf + tn * 12);
            uint2 a = *(const uint2*)(xr + 0);
            uint2 c = *(const uint2*)(xr + 2);
            xn0 = a.x; xn1 = a.y; xn2 = c.x; xn3 = c.y; xn4 = xr[4];
        }

        // Input projection (fp32, independent of h -> fills h-read latency).
        float xf[In];
        {
            h2 t0 = __builtin_bit_cast(h2, xc0), t1 = __builtin_bit_cast(h2, xc1);
            h2 t2 = __builtin_bit_cast(h2, xc2), t3 = __builtin_bit_cast(h2, xc3);
            h2 t4 = __builtin_bit_cast(h2, xc4);
            xf[0] = (float)t0[0]; xf[1] = (float)t0[1];
            xf[2] = (float)t1[0]; xf[3] = (float)t1[1];
            xf[4] = (float)t2[0]; xf[5] = (float)t2[1];
            xf[6] = (float)t3[0]; xf[7] = (float)t3[1];
            xf[8] = (float)t4[0]; xf[9] = (float)t4[1];
        }
        float gr = brz_r, gz = brz_z, gn = bi_n;
#pragma unroll
        for (int i = 0; i < In; ++i) {
            gr = fmaf(wir[i], xf[i], gr);
            gz = fmaf(wiz[i], xf[i], gz);
            gn = fmaf(win[i], xf[i], gn);
        }

        // Full 64-wide dot per lane: 96 v_dot2_f32_f16 in 6 independent chains.
        float ar0 = 0.f, ar1 = 0.f, az0 = 0.f, az1 = 0.f, an0 = bh_n, an1 = 0.f;
#pragma unroll
        for (int q = 0; q < 8; ++q) {
            uint4 uq = (q == 0) ? q0 : (q == 1) ? q1 : (q == 2) ? q2 : (q == 3) ? q3
                     : (q == 4) ? q4 : (q == 5) ? q5 : (q == 6) ? q6 : q7;
            h2 p0 = __builtin_bit_cast(h2, uq.x);
            h2 p1 = __builtin_bit_cast(h2, uq.y);
            h2 p2 = __builtin_bit_cast(h2, uq.z);
            h2 p3 = __builtin_bit_cast(h2, uq.w);
            const int k = 4 * q;
            ar0 = dot2(wr[k + 0], p0, ar0); az0 = dot2(wz[k + 0], p0, az0); an0 = dot2(wn[k + 0], p0, an0);
            ar1 = dot2(wr[k + 1], p1, ar1); az1 = dot2(wz[k + 1], p1, az1); an1 = dot2(wn[k + 1], p1, an1);
            ar0 = dot2(wr[k + 2], p2, ar0); az0 = dot2(wz[k + 2], p2, az0); an0 = dot2(wn[k + 2], p2, an0);
            ar1 = dot2(wr[k + 3], p3, ar1); az1 = dot2(wz[k + 3], p3, az1); an1 = dot2(wn[k + 3], p3, an1);
        }
        const float ar = ar0 + ar1;
        const float az = az0 + az1;
        const float an = an0 + an1;

        // Gates (prescaled): r,z sigmoid; n tanh. Saturation behaves correctly.
        const float r   = __builtin_amdgcn_rcpf(1.0f + __builtin_amdgcn_exp2f(gr + ar));
        const float z   = __builtin_amdgcn_rcpf(1.0f + __builtin_amdgcn_exp2f(gz + az));
        const float pn2 = fmaf(r, an, gn);                  // 2*log2e*(gn + r*an)
        const float e   = __builtin_amdgcn_exp2f(pn2);
        const float nn  = fmaf(-2.0f, __builtin_amdgcn_rcpf(e + 1.0f), 1.0f);
        const float hn  = fmaf(z, hold - nn, nn);           // (1-z)*n + z*h
        hold = hn;

        op[(size_t)t * Hn + j] = hn;  // coalesced 256B store, never waited on

        // Publish h for next step (f16). Same wave, in-order LDS pipe.
        hbuf[j] = __builtin_bit_cast(unsigned short, (_Float16)hn);

        xc0 = xn0; xc1 = xn1; xc2 = xn2; xc3 = xn3; xc4 = xn4;
    }
}

extern "C" void kernel_launch(void* const* d_in, const int* in_sizes, int n_in,
                              void* d_out, int out_size, void* d_ws, size_t ws_size,
                              hipStream_t stream) {
    gru_kernel<<<Bn, 64, 0, stream>>>(
        (const float*)d_in[0], (const float*)d_in[1], (const float*)d_in[2],
        (const float*)d_in[3], (const float*)d_in[4], (float*)d_out);
}

// Round 3
// 830.530 us; speedup vs baseline: 1.0746x; 1.0746x over previous
//
#include <hip/hip_runtime.h>

// GRU: B=256, T=2048, I=10, H=64, fp32 in/out.
// Round-6 theory: VGPR_Count=132 in BOTH r4/r5 with no scratch/LDS spill
// evidence => allocator caps at ~132 arch VGPRs; r5's ~180-reg live set was
// covered by per-step spill moves (real SIMD VALUBusy ~72% => ~330 instr/step,
// 2x source count). Fix: live set must fit UNDER the cap.
//   (a) 2-wave K-split, but K-half pairs on ADJACENT lanes (unit=lane>>1,
//       half=lane&1) so the reduce is __shfl_xor(x,1) = DPP quad-perm on the
//       VALU pipe (~8cy) instead of xor-32 permlane (~100cy).
//   (b) raw barrier: "s_waitcnt lgkmcnt(0); s_barrier" inline asm — waits the
//       h LDS write only, NEVER vmcnt => output store is truly fire-and-forget
//       (r4's __syncthreads drained vmcnt(0) = store L2-ack on critical path).
//       hbuf double-buffered => 1 barrier/step is race-free (each wave's own
//       lgkmcnt(0) drains its reads before it can pass the barrier).
//   (c) x staged in LDS as f32, rows padded to 48 B (b128-aligned): kills the
//       per-step unpack cvts AND keeps x in the lgkm domain (a global x load
//       would share vmcnt with stores and re-expose store-ack waits).
// Loop live set ~= 48 wgt + 30 proj + 16 hq + 10 x + 6 acc + misc ~= 125 < 128.

#define Bn 256
#define Tn 2048
#define In 10
#define Hn 64

typedef _Float16 h2 __attribute__((ext_vector_type(2)));

__device__ __forceinline__ float dot2(h2 a, h2 b, float c) {
    return __builtin_amdgcn_fdot2(a, b, c, false);
}

extern "C" __global__
__attribute__((amdgpu_flat_work_group_size(128, 128), amdgpu_waves_per_eu(1, 1)))
void gru_kernel(
    const float* __restrict__ noise,  // (B, T, I)
    const float* __restrict__ w_ih,   // (3H, I)
    const float* __restrict__ w_hh,   // (3H, H)
    const float* __restrict__ b_ih,   // (3H)
    const float* __restrict__ b_hh,   // (3H)
    float* __restrict__ out)          // (B, T, H)
{
    const int b   = blockIdx.x;
    const int tid = threadIdx.x;          // 0..127
    const int wv  = tid >> 6;             // wave 0/1
    const int l   = tid & 63;             // lane in wave
    const int u   = wv * 32 + (l >> 1);   // hidden unit 0..63 (32 per wave)
    const int kh  = l & 1;                // K-half: lane pair (2i, 2i+1)

    __shared__ alignas(16) float xs[Tn][12];            // x f32, 48 B rows (96 KB)
    __shared__ alignas(16) unsigned short hbuf[2][Hn];  // h f16, double-buffered

    // ---- stage x (f32, padded) into LDS ----
    {
        const float* xp = noise + (size_t)b * Tn * In;
        for (int r = tid; r < Tn; r += 128) {
            const float* px = xp + (size_t)r * In;      // 8B-aligned (r*40)
            float2 a0 = *(const float2*)(px + 0);
            float2 a1 = *(const float2*)(px + 2);
            float2 a2 = *(const float2*)(px + 4);
            float2 a3 = *(const float2*)(px + 6);
            float2 a4 = *(const float2*)(px + 8);
            float* d = xs[r];
            *(float2*)(d + 0) = a0;
            *(float2*)(d + 2) = a1;
            *(float2*)(d + 4) = a2;
            *(float2*)(d + 6) = a3;
            *(float2*)(d + 8) = a4;
        }
        if (tid < Hn) { hbuf[0][tid] = 0; hbuf[1][tid] = 0; }
    }

    // ---- per-lane weights, prescaled for exp2-native gates ----
    const float SR = -1.44269504f;   // -log2(e): sigmoid(v) = rcp(1+exp2(SR*v))
    const float SN =  2.88539008f;   // 2*log2(e): tanh(p) = 1-2*rcp(exp2(SN*p)+1)

    h2 wr[16], wz[16], wn[16];       // this lane's K-half of 3 W_hh rows (48 VGPRs)
    {
        const float* pr = w_hh + (size_t)(0 * Hn + u) * Hn + kh * 32;
        const float* pz = w_hh + (size_t)(1 * Hn + u) * Hn + kh * 32;
        const float* pn = w_hh + (size_t)(2 * Hn + u) * Hn + kh * 32;
#pragma unroll
        for (int k = 0; k < 16; ++k) {
            wr[k] = h2{(_Float16)(SR * pr[2 * k]), (_Float16)(SR * pr[2 * k + 1])};
            wz[k] = h2{(_Float16)(SR * pz[2 * k]), (_Float16)(SR * pz[2 * k + 1])};
            wn[k] = h2{(_Float16)(SN * pn[2 * k]), (_Float16)(SN * pn[2 * k + 1])};
        }
    }
    float wir[In], wiz[In], win[In];  // input-proj rows, fp32 (30 VGPRs)
#pragma unroll
    for (int i = 0; i < In; ++i) {
        wir[i] = SR * w_ih[(0 * Hn + u) * In + i];
        wiz[i] = SR * w_ih[(1 * Hn + u) * In + i];
        win[i] = SN * w_ih[(2 * Hn + u) * In + i];
    }
    const float brz_r = SR * (b_ih[0 * Hn + u] + b_hh[0 * Hn + u]);
    const float brz_z = SR * (b_ih[1 * Hn + u] + b_hh[1 * Hn + u]);
    const float bi_n  = SN * b_ih[2 * Hn + u];
    const float bh_n0 = (kh == 0) ? SN * b_hh[2 * Hn + u] : 0.0f;  // counted once

    // Pin weights (one-time, pre-loop; opaque to remat).
#pragma unroll
    for (int k = 0; k < 16; ++k)
        asm volatile("" : "+v"(wr[k]), "+v"(wz[k]), "+v"(wn[k]));
#pragma unroll
    for (int i = 0; i < In; ++i)
        asm volatile("" : "+v"(wir[i]), "+v"(wiz[i]), "+v"(win[i]));

    float hold = 0.0f;
    float* __restrict__ op = out + (size_t)b * Tn * Hn;

    __syncthreads();  // staging visible to both waves (one-time)

#pragma unroll 2
    for (int t = 0; t < Tn; ++t) {
        // x row (wave-uniform broadcast, lgkm domain) + this lane's h K-half.
        const float* xr = xs[t];
        float4 xA = *(const float4*)(xr + 0);   // t*48 is 16B-aligned
        float4 xB = *(const float4*)(xr + 4);
        float2 xC = *(const float2*)(xr + 8);

        const uint4* hq = (const uint4*)(&hbuf[t & 1][kh * 32]);
        uint4 q0 = hq[0], q1 = hq[1], q2 = hq[2], q3 = hq[3];

        // Input projection (f32, no unpack) — fills the h-read shadow.
        float gr = brz_r, gz = brz_z, gn = bi_n;
        gr = fmaf(wir[0], xA.x, gr); gz = fmaf(wiz[0], xA.x, gz); gn = fmaf(win[0], xA.x, gn);
        gr = fmaf(wir[1], xA.y, gr); gz = fmaf(wiz[1], xA.y, gz); gn = fmaf(win[1], xA.y, gn);
        gr = fmaf(wir[2], xA.z, gr); gz = fmaf(wiz[2], xA.z, gz); gn = fmaf(win[2], xA.z, gn);
        gr = fmaf(wir[3], xA.w, gr); gz = fmaf(wiz[3], xA.w, gz); gn = fmaf(win[3], xA.w, gn);
        gr = fmaf(wir[4], xB.x, gr); gz = fmaf(wiz[4], xB.x, gz); gn = fmaf(win[4], xB.x, gn);
        gr = fmaf(wir[5], xB.y, gr); gz = fmaf(wiz[5], xB.y, gz); gn = fmaf(win[5], xB.y, gn);
        gr = fmaf(wir[6], xB.z, gr); gz = fmaf(wiz[6], xB.z, gz); gn = fmaf(win[6], xB.z, gn);
        gr = fmaf(wir[7], xB.w, gr); gz = fmaf(wiz[7], xB.w, gz); gn = fmaf(win[7], xB.w, gn);
        gr = fmaf(wir[8], xC.x, gr); gz = fmaf(wiz[8], xC.x, gz); gn = fmaf(win[8], xC.x, gn);
        gr = fmaf(wir[9], xC.y, gr); gz = fmaf(wiz[9], xC.y, gz); gn = fmaf(win[9], xC.y, gn);

        // 48 v_dot2_f32_f16 over this lane's 32-wide K-half (6 indep chains).
        float ar0 = 0.f, ar1 = 0.f, az0 = 0.f, az1 = 0.f, an0 = bh_n0, an1 = 0.f;
#pragma unroll
        for (int q = 0; q < 4; ++q) {
            uint4 uq = (q == 0) ? q0 : (q == 1) ? q1 : (q == 2) ? q2 : q3;
            h2 p0 = __builtin_bit_cast(h2, uq.x);
            h2 p1 = __builtin_bit_cast(h2, uq.y);
            h2 p2 = __builtin_bit_cast(h2, uq.z);
            h2 p3 = __builtin_bit_cast(h2, uq.w);
            const int k = 4 * q;
            ar0 = dot2(wr[k + 0], p0, ar0); az0 = dot2(wz[k + 0], p0, az0); an0 = dot2(wn[k + 0], p0, an0);
            ar1 = dot2(wr[k + 1], p1, ar1); az1 = dot2(wz[k + 1], p1, az1); an1 = dot2(wn[k + 1], p1, an1);
            ar0 = dot2(wr[k + 2], p2, ar0); az0 = dot2(wz[k + 2], p2, az0); an0 = dot2(wn[k + 2], p2, an0);
            ar1 = dot2(wr[k + 3], p3, ar1); az1 = dot2(wz[k + 3], p3, az1); an1 = dot2(wn[k + 3], p3, an1);
        }
        float arp = ar0 + ar1, azp = az0 + az1, anp = an0 + an1;
        // K-half merge: adjacent-lane pair -> DPP quad-perm shuffle (VALU pipe).
        const float ar = arp + __shfl_xor(arp, 1);
        const float az = azp + __shfl_xor(azp, 1);
        const float an = anp + __shfl_xor(anp, 1);

        // Gates (prescaled): r,z sigmoid; n tanh. Saturation behaves correctly.
        const float r   = __builtin_amdgcn_rcpf(1.0f + __builtin_amdgcn_exp2f(gr + ar));
        const float z   = __builtin_amdgcn_rcpf(1.0f + __builtin_amdgcn_exp2f(gz + az));
        const float pn2 = fmaf(r, an, gn);                  // 2*log2e*(gn + r*an)
        const float e   = __builtin_amdgcn_exp2f(pn2);
        const float nn  = fmaf(-2.0f, __builtin_amdgcn_rcpf(e + 1.0f), 1.0f);
        const float hn  = fmaf(z, hold - nn, nn);           // (1-z)*n + z*h
        hold = hn;

        if (kh == 0) {
            // Even lanes own consecutive units -> contiguous 4B stores.
            op[(size_t)t * Hn + u] = hn;   // fire-and-forget: vmcnt NEVER waited
            hbuf[(t + 1) & 1][u] = __builtin_bit_cast(unsigned short, (_Float16)hn);
        }
        // Raw barrier: drain LDS write only (lgkm), never vmcnt. Memory clobber
        // stops any hbuf read/write from crossing.
        asm volatile("s_waitcnt lgkmcnt(0)\n\ts_barrier" ::: "memory");
    }
}

extern "C" void kernel_launch(void* const* d_in, const int* in_sizes, int n_in,
                              void* d_out, int out_size, void* d_ws, size_t ws_size,
                              hipStream_t stream) {
    gru_kernel<<<Bn, 128, 0, stream>>>(
        (const float*)d_in[0], (const float*)d_in[1], (const float*)d_in[2],
        (const float*)d_in[3], (const float*)d_in[4], (float*)d_out);
}

// Round 4
// 759.506 us; speedup vs baseline: 1.1751x; 1.0935x over previous
//
#include <hip/hip_runtime.h>

// GRU: B=256, T=2048, I=10, H=64, fp32 in/out.
// Round-7: WAVE SPECIALIZATION. r6 post-mortem: __shfl_xor lowers to
// ds_bpermute (LDS pipe, ~100cy, serial between dots and gates) and the
// per-step cross-wave handshake (ds_write -> lgkmcnt(0) -> s_barrier ->
// ds_read) costs ~250-300cy; K-split only exists to fit the reg cap.
// Fix: consumer wave runs the PURE recurrence with zero barriers / zero
// shuffles / zero vmem per step: full 96 pinned f16 weight VGPRs (fits now
// that the 30 proj regs and all addressing moved out), h broadcast via the
// r0/r5-verified same-wave LDS pattern (write -> in-order DS pipe -> 8x
// ds_read_b128, no handshake). Producer wave does x loads, input projection
// gi(t)=W_ih x+b (h-independent), and the global output stores; waves meet
// once per 8-step chunk via __syncthreads over double-buffered LDS rings
// (consumer vmcnt is always 0 -> its barrier drain is free; store-ack lands
// on the producer's ~2000cy slack).
// Consumer step model: h-read ~120 + 96 dot2 issue 192 + gates ~50 + ~15
// ~= 390 cy/step (vs 868 measured in r6).

#define Bn 256
#define Tn 2048
#define In 10
#define Hn 64
#define CH 8            // steps per chunk (ring half-depth)
#define NCH (Tn / CH)   // 256 chunks

typedef _Float16 h2 __attribute__((ext_vector_type(2)));

__device__ __forceinline__ float dot2(h2 a, h2 b, float c) {
    return __builtin_amdgcn_fdot2(a, b, c, false);
}
__device__ __forceinline__ h2 bc2(unsigned int u) {
    return __builtin_bit_cast(h2, u);
}

extern "C" __global__
__attribute__((amdgpu_flat_work_group_size(128, 128), amdgpu_waves_per_eu(1, 1)))
void gru_kernel(
    const float* __restrict__ noise,  // (B, T, I)
    const float* __restrict__ w_ih,   // (3H, I)
    const float* __restrict__ w_hh,   // (3H, H)
    const float* __restrict__ b_ih,   // (3H)
    const float* __restrict__ b_hh,   // (3H)
    float* __restrict__ out)          // (B, T, H)
{
    const int b   = blockIdx.x;
    const int tid = threadIdx.x;
    const int wv  = tid >> 6;  // 0 = consumer (recurrence), 1 = producer (proj+IO)
    const int j   = tid & 63;  // hidden unit 0..63

    // Double-buffered rings: gi (f32, SoA) and outputs. hbuf: h as f16 bits.
    __shared__ float gR[2][CH][Hn];
    __shared__ float gZ[2][CH][Hn];
    __shared__ float gN[2][CH][Hn];
    __shared__ float oR[2][CH][Hn];
    __shared__ alignas(16) unsigned short hbuf[Hn];

    const float SR = -1.44269504f;   // -log2(e): sigmoid(v) = rcp(1+exp2(SR*v))
    const float SN =  2.88539008f;   // 2*log2(e): tanh(p) = 1-2*rcp(exp2(SN*p)+1)

    // ---- producer state ----
    float wir[In], wiz[In], win[In];
    float Pbr = 0.f, Pbz = 0.f, Pbn = 0.f;
    const float* __restrict__ xp = noise + (size_t)b * Tn * In;
    float* __restrict__ op = out + (size_t)b * Tn * Hn;

    // ---- consumer state ----
    h2 wr[32], wz[32], wn[32];       // full 3x64 W_hh rows, f16, prescaled (96 VGPRs)
    float bh_n = 0.f;
    float hold = 0.f;

    if (wv == 1) {
        // Producer: prescaled input-projection rows + combined biases.
#pragma unroll
        for (int i = 0; i < In; ++i) {
            wir[i] = SR * w_ih[(0 * Hn + j) * In + i];
            wiz[i] = SR * w_ih[(1 * Hn + j) * In + i];
            win[i] = SN * w_ih[(2 * Hn + j) * In + i];
        }
        Pbr = SR * (b_ih[0 * Hn + j] + b_hh[0 * Hn + j]);
        Pbz = SR * (b_ih[1 * Hn + j] + b_hh[1 * Hn + j]);
        Pbn = SN * b_ih[2 * Hn + j];
    } else {
        // Consumer: full prescaled f16 W_hh rows for unit j, pinned.
        const float* pr = w_hh + (size_t)(0 * Hn + j) * Hn;
        const float* pz = w_hh + (size_t)(1 * Hn + j) * Hn;
        const float* pn = w_hh + (size_t)(2 * Hn + j) * Hn;
#pragma unroll
        for (int k = 0; k < 32; ++k) {
            wr[k] = h2{(_Float16)(SR * pr[2 * k]), (_Float16)(SR * pr[2 * k + 1])};
            wz[k] = h2{(_Float16)(SR * pz[2 * k]), (_Float16)(SR * pz[2 * k + 1])};
            wn[k] = h2{(_Float16)(SN * pn[2 * k]), (_Float16)(SN * pn[2 * k + 1])};
        }
#pragma unroll
        for (int k = 0; k < 32; ++k)
            asm volatile("" : "+v"(wr[k]), "+v"(wz[k]), "+v"(wn[k]));
        bh_n = SN * b_hh[2 * Hn + j];
        hbuf[j] = 0;  // f16 +0.0
    }

    auto produce = [&](int c) {  // gi for chunk c -> ring half (c&1)
        const int half = c & 1;
#pragma unroll
        for (int s = 0; s < CH; ++s) {
            const float* px = xp + (size_t)(c * CH + s) * In;
            float gr = Pbr, gz = Pbz, gn = Pbn;
#pragma unroll
            for (int i = 0; i < In; ++i) {
                const float xv = px[i];  // wave-uniform address
                gr = fmaf(wir[i], xv, gr);
                gz = fmaf(wiz[i], xv, gz);
                gn = fmaf(win[i], xv, gn);
            }
            gR[half][s][j] = gr;
            gZ[half][s][j] = gz;
            gN[half][s][j] = gn;
        }
    };
    auto flush = [&](int c) {  // outputs of chunk c -> global
        const int half = c & 1;
#pragma unroll
        for (int s = 0; s < CH; ++s)
            op[(size_t)(c * CH + s) * Hn + j] = oR[half][s][j];
    };

    if (wv == 1) produce(0);
    __syncthreads();

    for (int c = 0; c < NCH; ++c) {
        if (wv == 0) {
            // -------- consumer: 8 recurrence steps, no sync inside --------
            const int half = c & 1;
#pragma unroll
            for (int s = 0; s < CH; ++s) {
                // gi reads (needed only at the gates -> latency hidden).
                const float Pr = gR[half][s][j];
                const float Pz = gZ[half][s][j];
                const float Pn = gN[half][s][j];

                // h broadcast: 8x ds_read_b128 uniform addr. Same wave wrote
                // hbuf last step -> in-order DS pipe, no handshake needed.
                const uint4* hq4 = (const uint4*)hbuf;
                uint4 qA = hq4[0], qB = hq4[1], qC = hq4[2];

                float ar0 = 0.f, ar1 = 0.f, az0 = 0.f, az1 = 0.f;
                float an0 = bh_n, an1 = 0.f;
#define DOTG(g, Q)                                                              \
    do {                                                                        \
        h2 p0 = bc2((Q).x), p1 = bc2((Q).y), p2 = bc2((Q).z), p3 = bc2((Q).w); \
        ar0 = dot2(wr[4*(g)+0], p0, ar0); az0 = dot2(wz[4*(g)+0], p0, az0);    \
        an0 = dot2(wn[4*(g)+0], p0, an0);                                      \
        ar1 = dot2(wr[4*(g)+1], p1, ar1); az1 = dot2(wz[4*(g)+1], p1, az1);    \
        an1 = dot2(wn[4*(g)+1], p1, an1);                                      \
        ar0 = dot2(wr[4*(g)+2], p2, ar0); az0 = dot2(wz[4*(g)+2], p2, az0);    \
        an0 = dot2(wn[4*(g)+2], p2, an0);                                      \
        ar1 = dot2(wr[4*(g)+3], p3, ar1); az1 = dot2(wz[4*(g)+3], p3, az1);    \
        an1 = dot2(wn[4*(g)+3], p3, an1);                                      \
    } while (0)
                DOTG(0, qA); qA = hq4[3];
                DOTG(1, qB); qB = hq4[4];
                DOTG(2, qC); qC = hq4[5];
                DOTG(3, qA); qA = hq4[6];
                DOTG(4, qB); qB = hq4[7];
                DOTG(5, qC);
                DOTG(6, qA);
                DOTG(7, qB);
#undef DOTG
                const float ar = ar0 + ar1;
                const float az = az0 + az1;
                const float an = an0 + an1;

                // Gates (prescaled): r,z sigmoid; n tanh. Saturation correct.
                const float r   = __builtin_amdgcn_rcpf(1.0f + __builtin_amdgcn_exp2f(Pr + ar));
                const float z   = __builtin_amdgcn_rcpf(1.0f + __builtin_amdgcn_exp2f(Pz + az));
                const float pn2 = fmaf(r, an, Pn);           // 2*log2e*(gn + r*(...))
                const float e   = __builtin_amdgcn_exp2f(pn2);
                const float nn  = fmaf(-2.0f, __builtin_amdgcn_rcpf(e + 1.0f), 1.0f);
                const float hn  = fmaf(z, hold - nn, nn);    // (1-z)*n + z*h
                hold = hn;

                oR[half][s][j] = hn;  // producer stores it next phase
                hbuf[j] = __builtin_bit_cast(unsigned short, (_Float16)hn);
            }
        } else {
            // -------- producer: next gi chunk + flush previous outputs ------
            if (c + 1 < NCH) produce(c + 1);
            if (c > 0) flush(c - 1);
        }
        __syncthreads();  // consumer vmcnt==0 always -> drain is lgkm-only for it
    }
    if (wv == 1) flush(NCH - 1);
}

extern "C" void kernel_launch(void* const* d_in, const int* in_sizes, int n_in,
                              void* d_out, int out_size, void* d_ws, size_t ws_size,
                              hipStream_t stream) {
    gru_kernel<<<Bn, 128, 0, stream>>>(
        (const float*)d_in[0], (const float*)d_in[1], (const float*)d_in[2],
        (const float*)d_in[3], (const float*)d_in[4], (float*)d_out);
}

// Round 6
// 750.396 us; speedup vs baseline: 1.1894x; 1.0121x over previous
//
#include <hip/hip_runtime.h>

// GRU: B=256, T=2048, I=10, H=64, fp32 in/out.
// Round-9 = round-8 theory with the compile fix. r7 post-mortem: only 3 live
// h-quads => 5 serial LDS-latency rounds/step (~5x150=750cy, matches measured
// 772). The scheduler imposes this by sinking ds_reads to just-before-use.
// Fix: issue ALL 11 DS reads (8 h-quads + 3 gi) upfront, sched_barrier(0) so
// they can't sink, "+v" pins so they can't remat. r8 failed to compile:
// "+v" on a 128-bit uint4 is a tied indirect register input; pin per 32-bit
// COMPONENT instead (q0.x..q7.w are single VGPRs). Producer wave (x loads,
// gi projection, output stores) + 8-step chunk __syncthreads unchanged.
// Step model: first-read latency ~160 + 96 dot2 issue 192 (overlapping the
// pipelined read tail) + gates ~70 + writes ~15 ~= 460 cy vs 772 measured.

#define Bn 256
#define Tn 2048
#define In 10
#define Hn 64
#define CH 8            // steps per chunk (ring half-depth)
#define NCH (Tn / CH)   // 256 chunks

typedef _Float16 h2 __attribute__((ext_vector_type(2)));

__device__ __forceinline__ float dot2(h2 a, h2 b, float c) {
    return __builtin_amdgcn_fdot2(a, b, c, false);
}
__device__ __forceinline__ h2 bc2(unsigned int u) {
    return __builtin_bit_cast(h2, u);
}

extern "C" __global__
__attribute__((amdgpu_flat_work_group_size(128, 128), amdgpu_waves_per_eu(1, 1)))
void gru_kernel(
    const float* __restrict__ noise,  // (B, T, I)
    const float* __restrict__ w_ih,   // (3H, I)
    const float* __restrict__ w_hh,   // (3H, H)
    const float* __restrict__ b_ih,   // (3H)
    const float* __restrict__ b_hh,   // (3H)
    float* __restrict__ out)          // (B, T, H)
{
    const int b   = blockIdx.x;
    const int tid = threadIdx.x;
    const int wv  = tid >> 6;  // 0 = consumer (recurrence), 1 = producer (proj+IO)
    const int j   = tid & 63;  // hidden unit 0..63

    // Double-buffered rings: gi (f32, SoA) and outputs. hbuf: h as f16 bits.
    __shared__ float gR[2][CH][Hn];
    __shared__ float gZ[2][CH][Hn];
    __shared__ float gN[2][CH][Hn];
    __shared__ float oR[2][CH][Hn];
    __shared__ alignas(16) unsigned short hbuf[Hn];

    const float SR = -1.44269504f;   // -log2(e): sigmoid(v) = rcp(1+exp2(SR*v))
    const float SN =  2.88539008f;   // 2*log2(e): tanh(p) = 1-2*rcp(exp2(SN*p)+1)

    // ---- producer state ----
    float wir[In], wiz[In], win[In];
    float Pbr = 0.f, Pbz = 0.f, Pbn = 0.f;
    const float* __restrict__ xp = noise + (size_t)b * Tn * In;
    float* __restrict__ op = out + (size_t)b * Tn * Hn;

    // ---- consumer state ----
    h2 wr[32], wz[32], wn[32];       // full 3x64 W_hh rows, f16, prescaled (96 VGPRs)
    float bh_n = 0.f;
    float hold = 0.f;

    if (wv == 1) {
        // Producer: prescaled input-projection rows + combined biases.
#pragma unroll
        for (int i = 0; i < In; ++i) {
            wir[i] = SR * w_ih[(0 * Hn + j) * In + i];
            wiz[i] = SR * w_ih[(1 * Hn + j) * In + i];
            win[i] = SN * w_ih[(2 * Hn + j) * In + i];
        }
        Pbr = SR * (b_ih[0 * Hn + j] + b_hh[0 * Hn + j]);
        Pbz = SR * (b_ih[1 * Hn + j] + b_hh[1 * Hn + j]);
        Pbn = SN * b_ih[2 * Hn + j];
    } else {
        // Consumer: full prescaled f16 W_hh rows for unit j, pinned.
        const float* pr = w_hh + (size_t)(0 * Hn + j) * Hn;
        const float* pz = w_hh + (size_t)(1 * Hn + j) * Hn;
        const float* pn = w_hh + (size_t)(2 * Hn + j) * Hn;
#pragma unroll
        for (int k = 0; k < 32; ++k) {
            wr[k] = h2{(_Float16)(SR * pr[2 * k]), (_Float16)(SR * pr[2 * k + 1])};
            wz[k] = h2{(_Float16)(SR * pz[2 * k]), (_Float16)(SR * pz[2 * k + 1])};
            wn[k] = h2{(_Float16)(SN * pn[2 * k]), (_Float16)(SN * pn[2 * k + 1])};
        }
#pragma unroll
        for (int k = 0; k < 32; ++k)
            asm volatile("" : "+v"(wr[k]), "+v"(wz[k]), "+v"(wn[k]));
        bh_n = SN * b_hh[2 * Hn + j];
        hbuf[j] = 0;  // f16 +0.0
    }

    auto produce = [&](int c) {  // gi for chunk c -> ring half (c&1)
        const int half = c & 1;
#pragma unroll
        for (int s = 0; s < CH; ++s) {
            const float* px = xp + (size_t)(c * CH + s) * In;
            float gr = Pbr, gz = Pbz, gn = Pbn;
#pragma unroll
            for (int i = 0; i < In; ++i) {
                const float xv = px[i];  // wave-uniform address
                gr = fmaf(wir[i], xv, gr);
                gz = fmaf(wiz[i], xv, gz);
                gn = fmaf(win[i], xv, gn);
            }
            gR[half][s][j] = gr;
            gZ[half][s][j] = gz;
            gN[half][s][j] = gn;
        }
    };
    auto flush = [&](int c) {  // outputs of chunk c -> global
        const int half = c & 1;
#pragma unroll
        for (int s = 0; s < CH; ++s)
            op[(size_t)(c * CH + s) * Hn + j] = oR[half][s][j];
    };

    if (wv == 1) produce(0);
    __syncthreads();

    for (int c = 0; c < NCH; ++c) {
        if (wv == 0) {
            // -------- consumer: 8 recurrence steps, no sync inside --------
            const int half = c & 1;
#pragma unroll
            for (int s = 0; s < CH; ++s) {
                // Issue ALL DS reads upfront: 8 h-quads (uniform addr =
                // broadcast; post-write data, same wave, in-order DS pipe)
                // + 3 gi reads. sched_barrier stops the scheduler from
                // sinking them into the dot chain (the r5/r7 serializer);
                // per-component pins stop remat/sink of the loaded values.
                const uint4* hq4 = (const uint4*)hbuf;
                uint4 q0 = hq4[0], q1 = hq4[1], q2 = hq4[2], q3 = hq4[3];
                uint4 q4 = hq4[4], q5 = hq4[5], q6 = hq4[6], q7 = hq4[7];
                float ar0 = gR[half][s][j];   // acc init = gi_r (prescaled)
                float az0 = gZ[half][s][j];   // acc init = gi_z
                const float Pn = gN[half][s][j];
                __builtin_amdgcn_sched_barrier(0);
                asm volatile("" : "+v"(q0.x), "+v"(q0.y), "+v"(q0.z), "+v"(q0.w),
                                  "+v"(q1.x), "+v"(q1.y), "+v"(q1.z), "+v"(q1.w));
                asm volatile("" : "+v"(q2.x), "+v"(q2.y), "+v"(q2.z), "+v"(q2.w),
                                  "+v"(q3.x), "+v"(q3.y), "+v"(q3.z), "+v"(q3.w));
                asm volatile("" : "+v"(q4.x), "+v"(q4.y), "+v"(q4.z), "+v"(q4.w),
                                  "+v"(q5.x), "+v"(q5.y), "+v"(q5.z), "+v"(q5.w));
                asm volatile("" : "+v"(q6.x), "+v"(q6.y), "+v"(q6.z), "+v"(q6.w),
                                  "+v"(q7.x), "+v"(q7.y), "+v"(q7.z), "+v"(q7.w));

                float ar1 = 0.f, az1 = 0.f, an0 = bh_n, an1 = 0.f;
#define DOTG(g, Q)                                                              \
    do {                                                                        \
        h2 p0 = bc2((Q).x), p1 = bc2((Q).y), p2 = bc2((Q).z), p3 = bc2((Q).w); \
        ar0 = dot2(wr[4*(g)+0], p0, ar0); az0 = dot2(wz[4*(g)+0], p0, az0);    \
        an0 = dot2(wn[4*(g)+0], p0, an0);                                      \
        ar1 = dot2(wr[4*(g)+1], p1, ar1); az1 = dot2(wz[4*(g)+1], p1, az1);    \
        an1 = dot2(wn[4*(g)+1], p1, an1);                                      \
        ar0 = dot2(wr[4*(g)+2], p2, ar0); az0 = dot2(wz[4*(g)+2], p2, az0);    \
        an0 = dot2(wn[4*(g)+2], p2, an0);                                      \
        ar1 = dot2(wr[4*(g)+3], p3, ar1); az1 = dot2(wz[4*(g)+3], p3, az1);    \
        an1 = dot2(wn[4*(g)+3], p3, an1);                                      \
    } while (0)
                DOTG(0, q0);
                DOTG(1, q1);
                DOTG(2, q2);
                DOTG(3, q3);
                DOTG(4, q4);
                DOTG(5, q5);
                DOTG(6, q6);
                DOTG(7, q7);
#undef DOTG
                const float ar = ar0 + ar1;   // includes gi_r
                const float az = az0 + az1;   // includes gi_z
                const float an = an0 + an1;   // W_n.h + b_hh_n (excl. gi_n)

                // Gates (prescaled): r,z sigmoid; n tanh. Saturation correct.
                const float r   = __builtin_amdgcn_rcpf(1.0f + __builtin_amdgcn_exp2f(ar));
                const float z   = __builtin_amdgcn_rcpf(1.0f + __builtin_amdgcn_exp2f(az));
                const float pn2 = fmaf(r, an, Pn);           // 2*log2e*(gn + r*(...))
                const float e   = __builtin_amdgcn_exp2f(pn2);
                const float nn  = fmaf(-2.0f, __builtin_amdgcn_rcpf(e + 1.0f), 1.0f);
                const float hn  = fmaf(z, hold - nn, nn);    // (1-z)*n + z*h
                hold = hn;

                oR[half][s][j] = hn;  // producer stores it next phase
                hbuf[j] = __builtin_bit_cast(unsigned short, (_Float16)hn);
            }
        } else {
            // -------- producer: next gi chunk + flush previous outputs ------
            if (c + 1 < NCH) produce(c + 1);
            if (c > 0) flush(c - 1);
        }
        __syncthreads();  // consumer vmcnt==0 always -> drain is lgkm-only for it
    }
    if (wv == 1) flush(NCH - 1);
}

extern "C" void kernel_launch(void* const* d_in, const int* in_sizes, int n_in,
                              void* d_out, int out_size, void* d_ws, size_t ws_size,
                              hipStream_t stream) {
    gru_kernel<<<Bn, 128, 0, stream>>>(
        (const float*)d_in[0], (const float*)d_in[1], (const float*)d_in[2],
        (const float*)d_in[3], (const float*)d_in[4], (float*)d_out);
}